// Round 1
// baseline (2415.626 us; speedup 1.0000x reference)
//
#include <hip/hip_runtime.h>
#include <hip/hip_bf16.h>
#include <math.h>

#define TT 2048
#define DD 1024
#define NH 16
#define DHD 64
#define DFF 4096

// ---------------- LayerNorm: one block per row ----------------
__global__ __launch_bounds__(256) void ln_kernel(const float* __restrict__ x,
    const float* __restrict__ w, const float* __restrict__ b,
    float* __restrict__ out) {
  int row = blockIdx.x;
  const float4* xr = (const float4*)(x + (size_t)row * DD);
  float4 v = xr[threadIdx.x];
  float s  = v.x + v.y + v.z + v.w;
  float ss = v.x * v.x + v.y * v.y + v.z * v.z + v.w * v.w;
  for (int o = 32; o > 0; o >>= 1) {
    s  += __shfl_down(s, o);
    ss += __shfl_down(ss, o);
  }
  __shared__ float red[10];
  int lane = threadIdx.x & 63, wv = threadIdx.x >> 6;
  if (lane == 0) { red[wv] = s; red[4 + wv] = ss; }
  __syncthreads();
  if (threadIdx.x == 0) {
    float S  = red[0] + red[1] + red[2] + red[3];
    float SS = red[4] + red[5] + red[6] + red[7];
    float mu  = S * (1.0f / DD);
    float var = SS * (1.0f / DD) - mu * mu;
    red[8] = mu;
    red[9] = rsqrtf(var + 1e-5f);
  }
  __syncthreads();
  float mu = red[8], inv = red[9];
  float4 wv4 = ((const float4*)w)[threadIdx.x];
  float4 bv4 = ((const float4*)b)[threadIdx.x];
  float4 o4;
  o4.x = (v.x - mu) * inv * wv4.x + bv4.x;
  o4.y = (v.y - mu) * inv * wv4.y + bv4.y;
  o4.z = (v.z - mu) * inv * wv4.z + bv4.z;
  o4.w = (v.w - mu) * inv * wv4.w + bv4.w;
  ((float4*)(out + (size_t)row * DD))[threadIdx.x] = o4;
}

// ---------------- GEMM: C[M,N] = A[M,K] * B[N,K]^T + bias (+gelu) (+resid) ----
// 64x64 tile, BK=16, 256 threads, 4x4 micro-tile.
template<int FUSE_GELU>
__global__ __launch_bounds__(256) void gemm_bt(const float* __restrict__ A,
    const float* __restrict__ B, const float* __restrict__ bias,
    const float* __restrict__ resid, float* __restrict__ Cm,
    int M, int N, int K) {
  __shared__ float As[16][65];
  __shared__ float Bs[16][65];
  const int tx = threadIdx.x & 15;   // n dir
  const int ty = threadIdx.x >> 4;   // m dir
  const int row0 = blockIdx.y * 64;
  const int col0 = blockIdx.x * 64;
  float c[4][4] = {};
  for (int k0 = 0; k0 < K; k0 += 16) {
    for (int idx = threadIdx.x; idx < 64 * 16; idx += 256) {
      int mm = idx >> 4, kk = idx & 15;
      As[kk][mm] = A[(size_t)(row0 + mm) * K + k0 + kk];
      Bs[kk][mm] = B[(size_t)(col0 + mm) * K + k0 + kk];
    }
    __syncthreads();
#pragma unroll
    for (int kk = 0; kk < 16; ++kk) {
      float av[4], bv[4];
#pragma unroll
      for (int i = 0; i < 4; ++i) av[i] = As[kk][ty * 4 + i];
#pragma unroll
      for (int j = 0; j < 4; ++j) bv[j] = Bs[kk][tx * 4 + j];
#pragma unroll
      for (int i = 0; i < 4; ++i)
#pragma unroll
        for (int j = 0; j < 4; ++j) c[i][j] += av[i] * bv[j];
    }
    __syncthreads();
  }
#pragma unroll
  for (int i = 0; i < 4; ++i) {
    int row = row0 + ty * 4 + i;
#pragma unroll
    for (int j = 0; j < 4; ++j) {
      int col = col0 + tx * 4 + j;
      float v = c[i][j] + bias[col];
      if (FUSE_GELU) {
        float u = v;
        v = 0.5f * u * (1.0f + tanhf(0.7978845608028654f * (u + 0.044715f * u * u * u)));
      }
      if (resid) v += resid[(size_t)row * N + col];
      Cm[(size_t)row * N + col] = v;
    }
  }
}

// ---------------- gather heads: kqv[T,3D] -> Q/K/V [H,T,DH] ------------------
// to_heads: m.reshape(t, DH, H).transpose(2,0,1) => out[h,t,d] = m[t, d*H + h]
// split order is k, q, v.
__global__ __launch_bounds__(256) void gather_qkv(const float* __restrict__ kqv,
    float* __restrict__ Q, float* __restrict__ K, float* __restrict__ V) {
  int idx = blockIdx.x * 256 + threadIdx.x;   // over H*T*DH = 2M
  int d = idx & 63;
  int t = (idx >> 6) & (TT - 1);
  int h = idx >> 17;
  int col = d * NH + h;
  const float* rowp = kqv + (size_t)t * (3 * DD);
  K[idx] = rowp[col];
  Q[idx] = rowp[DD + col];
  V[idx] = rowp[2 * DD + col];
}

// ---------------- causal attention, fp32 streaming softmax -------------------
// grid (T/64, H); block 256. Each block: one head, 64 query rows.
// 4 threads per query row; each owns 16 keys (logit step) / 16 out dims (PV).
__global__ __launch_bounds__(256) void attn_kernel(const float* __restrict__ Q,
    const float* __restrict__ K, const float* __restrict__ V,
    float* __restrict__ hv) {
  const int h = blockIdx.y;
  const int qb = blockIdx.x;
  const int q0 = qb * 64;
  const int tid = threadIdx.x;
  const int r = tid >> 2;       // query row in tile
  const int g = tid & 3;
  const int j0 = g * 16;        // key sub-range / out-dim sub-range

  __shared__ float Qs[64][65];
  __shared__ float KPs[64][65]; // K tile, reused for P tile
  __shared__ float Vs[64][65];

  const float* Qh = Q + ((size_t)h * TT + q0) * DHD;
  const float* Kh = K + (size_t)h * TT * DHD;
  const float* Vh = V + (size_t)h * TT * DHD;

  for (int idx = tid; idx < 64 * 64; idx += 256) {
    int rr = idx >> 6, dd = idx & 63;
    Qs[rr][dd] = Qh[rr * 64 + dd];
  }

  float acc[16];
#pragma unroll
  for (int i = 0; i < 16; ++i) acc[i] = 0.0f;
  float m = -INFINITY, l = 0.0f;

  for (int kt = 0; kt <= qb; ++kt) {
    int k0 = kt * 64;
    for (int idx = tid; idx < 64 * 64; idx += 256) {
      int rr = idx >> 6, dd = idx & 63;
      KPs[rr][dd] = Kh[(size_t)(k0 + rr) * 64 + dd];
      Vs[rr][dd]  = Vh[(size_t)(k0 + rr) * 64 + dd];
    }
    __syncthreads();

    const bool diag = (kt == qb);
    float p[16];
    float tmax = -INFINITY;
#pragma unroll
    for (int jj = 0; jj < 16; ++jj) {
      int kk = j0 + jj;
      float dot = 0.0f;
#pragma unroll 8
      for (int d = 0; d < 64; ++d) dot += Qs[r][d] * KPs[kk][d];
      float logit = 8.0f * dot;   // * sqrt(DH)
      bool masked = diag && (k0 + kk > q0 + r);
      p[jj] = masked ? -INFINITY : logit;
      if (!masked) tmax = fmaxf(tmax, logit);
    }
    tmax = fmaxf(tmax, __shfl_xor(tmax, 1));
    tmax = fmaxf(tmax, __shfl_xor(tmax, 2));
    float newm = fmaxf(m, tmax);
    float alpha = (m == -INFINITY) ? 0.0f : __expf(m - newm);
    float s = 0.0f;
#pragma unroll
    for (int jj = 0; jj < 16; ++jj) {
      float pv = (p[jj] == -INFINITY) ? 0.0f : __expf(p[jj] - newm);
      p[jj] = pv;
      s += pv;
    }
    s += __shfl_xor(s, 1);
    s += __shfl_xor(s, 2);
    l = l * alpha + s;
    m = newm;
#pragma unroll
    for (int i = 0; i < 16; ++i) acc[i] *= alpha;

    __syncthreads();   // done reading K before overwriting with P
#pragma unroll
    for (int jj = 0; jj < 16; ++jj) KPs[r][j0 + jj] = p[jj];
    __syncthreads();

    for (int kk2 = 0; kk2 < 64; ++kk2) {
      float pv = KPs[r][kk2];
#pragma unroll
      for (int i = 0; i < 16; ++i) acc[i] += pv * Vs[kk2][j0 + i];
    }
    __syncthreads();   // before next tile's K/V load
  }

  float invl = 1.0f / l;
  float* outp = hv + (size_t)(q0 + r) * DD + h * DHD + j0;
#pragma unroll
  for (int i = 0; i < 16; ++i) outp[i] = acc[i] * invl;
}

// ---------------- launch ----------------
extern "C" void kernel_launch(void* const* d_in, const int* in_sizes, int n_in,
                              void* d_out, int out_size, void* d_ws, size_t ws_size,
                              hipStream_t stream) {
  const float* x     = (const float*)d_in[0];
  const float* w_kqv = (const float*)d_in[1];
  const float* b_kqv = (const float*)d_in[2];
  const float* w_o   = (const float*)d_in[3];
  const float* b_o   = (const float*)d_in[4];
  const float* ln1_w = (const float*)d_in[5];
  const float* ln1_b = (const float*)d_in[6];
  const float* ln2_w = (const float*)d_in[7];
  const float* ln2_b = (const float*)d_in[8];
  const float* w_up  = (const float*)d_in[9];
  const float* b_up  = (const float*)d_in[10];
  const float* w_dn  = (const float*)d_in[11];
  const float* b_dn  = (const float*)d_in[12];
  float* out = (float*)d_out;

  float* ws = (float*)d_ws;
  const size_t TD = (size_t)TT * DD;          // 2,097,152
  float* h_buf  = ws;                          // [T,D]   (reused for h2)
  float* kqv    = ws + TD;                     // [T,3D]  (later reused for z1 [T,DFF])
  float* Qg     = ws + 4 * TD;                 // [H,T,DH]
  float* Kg     = ws + 5 * TD;
  float* Vg     = ws + 6 * TD;
  float* hv     = ws + 7 * TD;                 // [T,D]
  float* x2     = ws + 8 * TD;                 // [T,D]
  float* z1     = kqv;                         // [T,DFF] overlaps kqv+Qg (both dead)

  // 1. h = LN1(x)
  ln_kernel<<<TT, 256, 0, stream>>>(x, ln1_w, ln1_b, h_buf);
  // 2. kqv = h @ w_kqv^T + b_kqv
  gemm_bt<0><<<dim3(3 * DD / 64, TT / 64), 256, 0, stream>>>(
      h_buf, w_kqv, b_kqv, nullptr, kqv, TT, 3 * DD, DD);
  // 3. gather heads
  gather_qkv<<<(NH * TT * DHD) / 256, 256, 0, stream>>>(kqv, Qg, Kg, Vg);
  // 4. attention -> hv [T, D] (head-slow layout)
  attn_kernel<<<dim3(TT / 64, NH), 256, 0, stream>>>(Qg, Kg, Vg, hv);
  // 5. x2 = x + hv @ w_o^T + b_o
  gemm_bt<0><<<dim3(DD / 64, TT / 64), 256, 0, stream>>>(
      hv, w_o, b_o, x, x2, TT, DD, DD);
  // 6. h2 = LN2(x2)
  ln_kernel<<<TT, 256, 0, stream>>>(x2, ln2_w, ln2_b, h_buf);
  // 7. z1 = gelu(h2 @ w_up^T + b_up)
  gemm_bt<1><<<dim3(DFF / 64, TT / 64), 256, 0, stream>>>(
      h_buf, w_up, b_up, nullptr, z1, TT, DFF, DD);
  // 8. out = x2 + z1 @ w_dn^T + b_dn
  gemm_bt<0><<<dim3(DD / 64, TT / 64), 256, 0, stream>>>(
      z1, w_dn, b_dn, x2, out, TT, DD, DFF);
}

// Round 2
// 289.795 us; speedup vs baseline: 8.3356x; 8.3356x over previous
//
#include <hip/hip_runtime.h>
#include <math.h>

#define TT 2048
#define DD 1024
#define NH 16
#define DHD 64
#define DFF 4096

typedef __attribute__((ext_vector_type(8))) short short8;
typedef __attribute__((ext_vector_type(4))) float f32x4;

#define MFMA16(a, b, c) __builtin_amdgcn_mfma_f32_16x16x32_bf16(a, b, c, 0, 0, 0)
#define GLDS16(gp, lp) __builtin_amdgcn_global_load_lds( \
    (const __attribute__((address_space(1))) void*)(gp), \
    (__attribute__((address_space(3))) void*)(lp), 16, 0, 0)

static __device__ __forceinline__ unsigned short f2b(float f) {
  unsigned u = __builtin_bit_cast(unsigned, f);
  u = u + 0x7fffu + ((u >> 16) & 1u);
  return (unsigned short)(u >> 16);
}
static __device__ __forceinline__ float b2f(unsigned short b) {
  return __builtin_bit_cast(float, (unsigned)b << 16);
}

// ---------------- fp32 -> bf16 convert (weights) ----------------
__global__ __launch_bounds__(256) void f2b_kernel(const float* __restrict__ in,
    unsigned short* __restrict__ out, int n4) {
  int i = blockIdx.x * 256 + threadIdx.x;
  if (i >= n4) return;
  float4 v = ((const float4*)in)[i];
  ushort4 o;
  o.x = f2b(v.x); o.y = f2b(v.y); o.z = f2b(v.z); o.w = f2b(v.w);
  ((ushort4*)out)[i] = o;
}

// ---------------- LayerNorm (fp32 in, bf16 out) ----------------
__global__ __launch_bounds__(256) void ln_kernel(const float* __restrict__ x,
    const float* __restrict__ w, const float* __restrict__ b,
    unsigned short* __restrict__ out) {
  int row = blockIdx.x;
  const float4* xr = (const float4*)(x + (size_t)row * DD);
  float4 v = xr[threadIdx.x];
  float s  = v.x + v.y + v.z + v.w;
  float ss = v.x * v.x + v.y * v.y + v.z * v.z + v.w * v.w;
  for (int o = 32; o > 0; o >>= 1) {
    s  += __shfl_down(s, o);
    ss += __shfl_down(ss, o);
  }
  __shared__ float red[10];
  int lane = threadIdx.x & 63, wv = threadIdx.x >> 6;
  if (lane == 0) { red[wv] = s; red[4 + wv] = ss; }
  __syncthreads();
  if (threadIdx.x == 0) {
    float S  = red[0] + red[1] + red[2] + red[3];
    float SS = red[4] + red[5] + red[6] + red[7];
    float mu  = S * (1.0f / DD);
    float var = SS * (1.0f / DD) - mu * mu;
    red[8] = mu;
    red[9] = rsqrtf(var + 1e-5f);
  }
  __syncthreads();
  float mu = red[8], inv = red[9];
  float4 wv4 = ((const float4*)w)[threadIdx.x];
  float4 bv4 = ((const float4*)b)[threadIdx.x];
  ushort4 o4;
  o4.x = f2b((v.x - mu) * inv * wv4.x + bv4.x);
  o4.y = f2b((v.y - mu) * inv * wv4.y + bv4.y);
  o4.z = f2b((v.z - mu) * inv * wv4.z + bv4.z);
  o4.w = f2b((v.w - mu) * inv * wv4.w + bv4.w);
  ((ushort4*)(out + (size_t)row * DD))[threadIdx.x] = o4;
}

// ---------------- bf16 MFMA GEMM: C[M,N] = A[M,K] * B[N,K]^T (+bias/gelu/resid)
// 128x128 tile, BK=32, 256 threads (4 waves 2x2), 4x4 16x16 frags per wave.
template<int FUSE_GELU, int OUT_BF16, int HAS_RESID>
__global__ __launch_bounds__(256) void gemm_mfma(
    const unsigned short* __restrict__ A,   // [M,K] bf16
    const unsigned short* __restrict__ Bw,  // [N,K] bf16
    const float* __restrict__ bias,         // [N]
    const float* __restrict__ resid,        // [M,N] fp32
    void* __restrict__ Cout,
    int M, int N, int K) {
  __shared__ unsigned short As[128 * 32];
  __shared__ unsigned short Bs[128 * 32];
  const int tid = threadIdx.x;
  const int w = tid >> 6, l = tid & 63;
  const int l15 = l & 15, lhi = l >> 4;
  const int row0 = blockIdx.y * 128, col0 = blockIdx.x * 128;
  const int wm = (w >> 1) * 64, wn = (w & 1) * 64;

  f32x4 acc[4][4] = {};

  // staging: LDS linear [128 rows][32 bf16]; wave w covers rows w*32..w*32+31
  const int srow = w * 32 + (l >> 2);
  const int scolb = (l & 3) * 16;
  const char* aS0 = (const char*)A + ((size_t)(row0 + srow) * K) * 2 + scolb;
  const char* aS1 = aS0 + (size_t)16 * K * 2;
  const char* bS0 = (const char*)Bw + ((size_t)(col0 + srow) * K) * 2 + scolb;
  const char* bS1 = bS0 + (size_t)16 * K * 2;
  char* aL = (char*)As + w * 2048;
  char* bL = (char*)Bs + w * 2048;

  for (int k0 = 0; k0 < K; k0 += 32) {
    __syncthreads();                 // prior compute done before overwrite
    GLDS16(aS0, aL);
    GLDS16(aS1, aL + 1024);
    GLDS16(bS0, bL);
    GLDS16(bS1, bL + 1024);
    aS0 += 64; aS1 += 64; bS0 += 64; bS1 += 64;
    __syncthreads();                 // staging visible (drains vmcnt)

    short8 af[4], bf[4];
#pragma unroll
    for (int mi = 0; mi < 4; ++mi)
      af[mi] = *(const short8*)((const char*)As + (wm + mi * 16 + l15) * 64 + lhi * 16);
#pragma unroll
    for (int ni = 0; ni < 4; ++ni)
      bf[ni] = *(const short8*)((const char*)Bs + (wn + ni * 16 + l15) * 64 + lhi * 16);
#pragma unroll
    for (int mi = 0; mi < 4; ++mi)
#pragma unroll
      for (int ni = 0; ni < 4; ++ni)
        acc[mi][ni] = MFMA16(af[mi], bf[ni], acc[mi][ni]);
  }

#pragma unroll
  for (int mi = 0; mi < 4; ++mi) {
#pragma unroll
    for (int r = 0; r < 4; ++r) {
      size_t row = (size_t)(row0 + wm + mi * 16 + lhi * 4 + r);
#pragma unroll
      for (int ni = 0; ni < 4; ++ni) {
        int col = col0 + wn + ni * 16 + l15;
        float v = acc[mi][ni][r] + bias[col];
        if (FUSE_GELU) {
          float u = v;
          v = 0.5f * u * (1.0f + tanhf(0.7978845608028654f * (u + 0.044715f * u * u * u)));
        }
        if (HAS_RESID) v += resid[row * N + col];
        if (OUT_BF16) ((unsigned short*)Cout)[row * N + col] = f2b(v);
        else          ((float*)Cout)[row * N + col] = v;
      }
    }
  }
}

// ---------------- gather heads: kqv[T,3D] bf16 -> K/Q/V [H,T,DH] bf16 --------
// out[h,t,d] = kqv[t, sec*D + d*NH + h]; split order k,q,v; Q pre-scaled by 8.
__global__ __launch_bounds__(256) void gather_qkv(const unsigned short* __restrict__ kqv,
    unsigned short* __restrict__ Q, unsigned short* __restrict__ K,
    unsigned short* __restrict__ V) {
  int idx = blockIdx.x * 256 + threadIdx.x;   // over H*T*DH = 2^21
  int d = idx & 63;
  int t = (idx >> 6) & (TT - 1);
  int h = idx >> 17;
  int col = d * NH + h;
  const unsigned short* rowp = kqv + (size_t)t * (3 * DD);
  K[idx] = rowp[col];
  Q[idx] = f2b(b2f(rowp[DD + col]) * 8.0f);   // * sqrt(DH), exact in bf16
  V[idx] = rowp[2 * DD + col];
}

// ---------------- MFMA flash attention -------------------------------------
// grid (T/64, H), 256 threads = 4 waves; wave w owns q-rows w*16..w*16+15.
// K tile staged via global_load_lds with pre-swizzled source; V reg-transposed
// into swizzled Vt[d][k]; P per-wave-private swizzled LDS.
__global__ __launch_bounds__(256) void attn_mfma(
    const unsigned short* __restrict__ Q,   // [H,T,DH] bf16, pre-scaled
    const unsigned short* __restrict__ K,
    const unsigned short* __restrict__ V,
    unsigned short* __restrict__ hv) {      // [T,D] bf16, head-slow cols
  const int h = blockIdx.y;
  const int qb = gridDim.x - 1 - blockIdx.x;   // heavy blocks first
  const int q0 = qb * 64;
  const int tid = threadIdx.x;
  const int w = tid >> 6, l = tid & 63;
  const int l15 = l & 15, lhi = l >> 4;

  __shared__ unsigned short Ks[64 * 64];       // swizzled [key][dim]
  __shared__ unsigned short Vt[64 * 64];       // swizzled [dim][key]
  __shared__ unsigned short Ps[4][16 * 64];    // per-wave [16 q][64 k] swizzled

  const unsigned short* Kh = K + (size_t)h * TT * DHD;
  const unsigned short* Vh = V + (size_t)h * TT * DHD;

  // Q fragments (A-operand): lane holds Q[q0+w*16+l15][lhi*8+j (+32)]
  const unsigned short* Qbase = Q + ((size_t)h * TT + q0 + w * 16 + l15) * DHD;
  short8 qf0 = *(const short8*)(Qbase + lhi * 8);
  short8 qf1 = *(const short8*)(Qbase + 32 + lhi * 8);

  f32x4 oacc[4] = {};
  float m[4], lsum[4];
#pragma unroll
  for (int r = 0; r < 4; ++r) { m[r] = -INFINITY; lsum[r] = 0.0f; }

  // K staging geometry (global_load_lds, pre-swizzled source)
  const int krow = w * 16 + (l >> 3);               // +8 for issue 1
  const int kswz = (krow & 7) << 4;                 // same for krow+8
  const int kcolb = ((l & 7) * 16) ^ kswz;
  char* kL = (char*)Ks + w * 2048;

  for (int kt = 0; kt <= qb; ++kt) {
    const int k0 = kt * 64;
    __syncthreads();   // previous tile's LDS reads complete

    // stage K tile (2 issues per wave)
    GLDS16((const char*)(Kh + (size_t)(k0 + krow) * DHD) + kcolb, kL);
    GLDS16((const char*)(Kh + (size_t)(k0 + krow + 8) * DHD) + kcolb, kL + 1024);

    // stage V transposed: lane loads V[k0+l][w*8..+7] and [+32..], scatters
    {
      const char* vS = (const char*)(Vh + (size_t)(k0 + l) * DHD) + w * 16;
      short8 v0 = *(const short8*)vS;
      short8 v1 = *(const short8*)(vS + 64);
#pragma unroll
      for (int j = 0; j < 8; ++j) {
        int d = w * 8 + j;
        *(unsigned short*)((char*)Vt + d * 128 + ((2 * l) ^ (j << 4))) =
            (unsigned short)v0[j];
        *(unsigned short*)((char*)Vt + (d + 32) * 128 + ((2 * l) ^ (j << 4))) =
            (unsigned short)v1[j];
      }
    }
    __syncthreads();   // staging visible

    // ---- S = Q K^T (rows = local q lhi*4+r, cols = key nt*16+l15) ----
    f32x4 sacc[4] = {};
    {
      const char* kr = (const char*)Ks;
      int swz = (l15 & 7) << 4;
#pragma unroll
      for (int nt = 0; nt < 4; ++nt) {
        const char* rowp = kr + (nt * 16 + l15) * 128;
        short8 kb0 = *(const short8*)(rowp + ((lhi * 16) ^ swz));
        short8 kb1 = *(const short8*)(rowp + ((64 + lhi * 16) ^ swz));
        sacc[nt] = MFMA16(qf0, kb0, sacc[nt]);
        sacc[nt] = MFMA16(qf1, kb1, sacc[nt]);
      }
    }

    // ---- causal mask (diag tile only) ----
    if (kt == qb) {
      const int qrow = w * 16 + lhi * 4;      // local; k0 == q0
#pragma unroll
      for (int nt = 0; nt < 4; ++nt)
#pragma unroll
        for (int r = 0; r < 4; ++r)
          if (nt * 16 + l15 > qrow + r) sacc[nt][r] = -INFINITY;
    }

    // ---- online softmax ----
    float mnew[4], al[4];
#pragma unroll
    for (int r = 0; r < 4; ++r) {
      float t = fmaxf(fmaxf(sacc[0][r], sacc[1][r]), fmaxf(sacc[2][r], sacc[3][r]));
      t = fmaxf(t, __shfl_xor(t, 1));
      t = fmaxf(t, __shfl_xor(t, 2));
      t = fmaxf(t, __shfl_xor(t, 4));
      t = fmaxf(t, __shfl_xor(t, 8));
      mnew[r] = fmaxf(m[r], t);
      al[r] = __expf(m[r] - mnew[r]);
      m[r] = mnew[r];
    }
#pragma unroll
    for (int r = 0; r < 4; ++r) {
      float s = 0.0f;
#pragma unroll
      for (int nt = 0; nt < 4; ++nt) {
        float p = __expf(sacc[nt][r] - mnew[r]);
        sacc[nt][r] = p;
        s += p;
      }
      s += __shfl_xor(s, 1);
      s += __shfl_xor(s, 2);
      s += __shfl_xor(s, 4);
      s += __shfl_xor(s, 8);
      lsum[r] = lsum[r] * al[r] + s;
#pragma unroll
      for (int dt = 0; dt < 4; ++dt) oacc[dt][r] *= al[r];
    }

    // ---- P -> per-wave LDS (bf16, swizzled) ----
    {
      char* pw = (char*)Ps[w];
#pragma unroll
      for (int r = 0; r < 4; ++r) {
        int prow = lhi * 4 + r;
        char* pp = pw + prow * 128;
        int swz = (prow & 7) << 4;
#pragma unroll
        for (int nt = 0; nt < 4; ++nt)
          *(unsigned short*)(pp + ((nt * 32 + l15 * 2) ^ swz)) = f2b(sacc[nt][r]);
      }
    }

    // ---- O += P V ----
    {
      const char* pr = (const char*)Ps[w] + l15 * 128;
      int pswz = (l15 & 7) << 4;
      short8 pa0 = *(const short8*)(pr + ((lhi * 16) ^ pswz));
      short8 pa1 = *(const short8*)(pr + ((64 + lhi * 16) ^ pswz));
      int vswz = (l15 & 7) << 4;
#pragma unroll
      for (int dt = 0; dt < 4; ++dt) {
        const char* vr = (const char*)Vt + (dt * 16 + l15) * 128;
        short8 vb0 = *(const short8*)(vr + ((lhi * 16) ^ vswz));
        short8 vb1 = *(const short8*)(vr + ((64 + lhi * 16) ^ vswz));
        oacc[dt] = MFMA16(pa0, vb0, oacc[dt]);
        oacc[dt] = MFMA16(pa1, vb1, oacc[dt]);
      }
    }
  }

  // ---- epilogue: normalize, write hv[q, h*64 + d] bf16 ----
#pragma unroll
  for (int r = 0; r < 4; ++r) {
    float inv = 1.0f / lsum[r];
    size_t orow = (size_t)(q0 + w * 16 + lhi * 4 + r) * DD + h * 64;
#pragma unroll
    for (int dt = 0; dt < 4; ++dt)
      hv[orow + dt * 16 + l15] = f2b(oacc[dt][r] * inv);
  }
}

// ---------------- launch ----------------
extern "C" void kernel_launch(void* const* d_in, const int* in_sizes, int n_in,
                              void* d_out, int out_size, void* d_ws, size_t ws_size,
                              hipStream_t stream) {
  const float* x     = (const float*)d_in[0];
  const float* w_kqv = (const float*)d_in[1];
  const float* b_kqv = (const float*)d_in[2];
  const float* w_o   = (const float*)d_in[3];
  const float* b_o   = (const float*)d_in[4];
  const float* ln1_w = (const float*)d_in[5];
  const float* ln1_b = (const float*)d_in[6];
  const float* ln2_w = (const float*)d_in[7];
  const float* ln2_b = (const float*)d_in[8];
  const float* w_up  = (const float*)d_in[9];
  const float* b_up  = (const float*)d_in[10];
  const float* w_dn  = (const float*)d_in[11];
  const float* b_dn  = (const float*)d_in[12];
  float* out = (float*)d_out;

  char* W = (char*)d_ws;
  unsigned short* wkqv_b = (unsigned short*)(W);                 // 6 MB
  unsigned short* wo_b   = (unsigned short*)(W + 6291456);       // 2 MB
  unsigned short* wup_b  = (unsigned short*)(W + 8388608);       // 8 MB
  unsigned short* wdn_b  = (unsigned short*)(W + 16777216);      // 8 MB
  unsigned short* h_b    = (unsigned short*)(W + 25165824);      // 4 MB
  unsigned short* kqz    = (unsigned short*)(W + 29360128);      // 16 MB (kqv, then z1)
  unsigned short* Qg     = (unsigned short*)(W + 46137344);      // 4 MB
  unsigned short* Kg     = (unsigned short*)(W + 50331648);      // 4 MB
  unsigned short* Vg     = (unsigned short*)(W + 54525952);      // 4 MB
  unsigned short* hv_b   = (unsigned short*)(W + 58720256);      // 4 MB
  float*          x2     = (float*)(W + 62914560);               // 8 MB

  // weight conversion fp32 -> bf16
  f2b_kernel<<<(3 * DD * DD / 4 + 255) / 256, 256, 0, stream>>>(w_kqv, wkqv_b, 3 * DD * DD / 4);
  f2b_kernel<<<(DD * DD / 4 + 255) / 256, 256, 0, stream>>>(w_o, wo_b, DD * DD / 4);
  f2b_kernel<<<(DFF * DD / 4 + 255) / 256, 256, 0, stream>>>(w_up, wup_b, DFF * DD / 4);
  f2b_kernel<<<(DD * DFF / 4 + 255) / 256, 256, 0, stream>>>(w_dn, wdn_b, DD * DFF / 4);

  // 1. h = LN1(x)
  ln_kernel<<<TT, 256, 0, stream>>>(x, ln1_w, ln1_b, h_b);
  // 2. kqv = h @ w_kqv^T + b_kqv   (bf16 out)
  gemm_mfma<0, 1, 0><<<dim3(3 * DD / 128, TT / 128), 256, 0, stream>>>(
      h_b, wkqv_b, b_kqv, nullptr, kqz, TT, 3 * DD, DD);
  // 3. gather heads (Q pre-scaled by sqrt(DH))
  gather_qkv<<<(NH * TT * DHD) / 256, 256, 0, stream>>>(kqz, Qg, Kg, Vg);
  // 4. attention -> hv bf16
  attn_mfma<<<dim3(TT / 64, NH), 256, 0, stream>>>(Qg, Kg, Vg, hv_b);
  // 5. x2 = x + hv @ w_o^T + b_o   (fp32 out)
  gemm_mfma<0, 0, 1><<<dim3(DD / 128, TT / 128), 256, 0, stream>>>(
      hv_b, wo_b, b_o, x, x2, TT, DD, DD);
  // 6. h2 = LN2(x2)
  ln_kernel<<<TT, 256, 0, stream>>>(x2, ln2_w, ln2_b, h_b);
  // 7. z1 = gelu(h2 @ w_up^T + b_up)  (bf16 out)
  gemm_mfma<1, 1, 0><<<dim3(DFF / 128, TT / 128), 256, 0, stream>>>(
      h_b, wup_b, b_up, nullptr, kqz, TT, DFF, DD);
  // 8. out = x2 + z1 @ w_dn^T + b_dn  (fp32 out)
  gemm_mfma<0, 0, 1><<<dim3(DD / 128, TT / 128), 256, 0, stream>>>(
      kqz, wdn_b, b_dn, x2, out, TT, DD, DFF);
}

// Round 3
// 211.303 us; speedup vs baseline: 11.4320x; 1.3715x over previous
//
#include <hip/hip_runtime.h>
#include <math.h>

#define TT 2048
#define DD 1024
#define NH 16
#define DHD 64
#define DFF 4096

typedef __attribute__((ext_vector_type(8))) short short8;
typedef __attribute__((ext_vector_type(4))) float f32x4;

#define MFMA16(a, b, c) __builtin_amdgcn_mfma_f32_16x16x32_bf16(a, b, c, 0, 0, 0)
#define GLDS16(gp, lp) __builtin_amdgcn_global_load_lds( \
    (const __attribute__((address_space(1))) void*)(gp), \
    (__attribute__((address_space(3))) void*)(lp), 16, 0, 0)

static __device__ __forceinline__ unsigned short f2b(float f) {
  unsigned u = __builtin_bit_cast(unsigned, f);
  u = u + 0x7fffu + ((u >> 16) & 1u);
  return (unsigned short)(u >> 16);
}
static __device__ __forceinline__ float b2f(unsigned short b) {
  return __builtin_bit_cast(float, (unsigned)b << 16);
}

// ---------------- fp32 -> bf16 convert (weights) ----------------
__global__ __launch_bounds__(256) void f2b_kernel(const float* __restrict__ in,
    unsigned short* __restrict__ out, int n4) {
  int i = blockIdx.x * 256 + threadIdx.x;
  if (i >= n4) return;
  float4 v = ((const float4*)in)[i];
  ushort4 o;
  o.x = f2b(v.x); o.y = f2b(v.y); o.z = f2b(v.z); o.w = f2b(v.w);
  ((ushort4*)out)[i] = o;
}

// ---------------- LayerNorm (fp32 in, bf16 out) ----------------
__global__ __launch_bounds__(256) void ln_kernel(const float* __restrict__ x,
    const float* __restrict__ w, const float* __restrict__ b,
    unsigned short* __restrict__ out) {
  int row = blockIdx.x;
  const float4* xr = (const float4*)(x + (size_t)row * DD);
  float4 v = xr[threadIdx.x];
  float s  = v.x + v.y + v.z + v.w;
  float ss = v.x * v.x + v.y * v.y + v.z * v.z + v.w * v.w;
  for (int o = 32; o > 0; o >>= 1) {
    s  += __shfl_down(s, o);
    ss += __shfl_down(ss, o);
  }
  __shared__ float red[10];
  int lane = threadIdx.x & 63, wv = threadIdx.x >> 6;
  if (lane == 0) { red[wv] = s; red[4 + wv] = ss; }
  __syncthreads();
  if (threadIdx.x == 0) {
    float S  = red[0] + red[1] + red[2] + red[3];
    float SS = red[4] + red[5] + red[6] + red[7];
    float mu  = S * (1.0f / DD);
    float var = SS * (1.0f / DD) - mu * mu;
    red[8] = mu;
    red[9] = rsqrtf(var + 1e-5f);
  }
  __syncthreads();
  float mu = red[8], inv = red[9];
  float4 wv4 = ((const float4*)w)[threadIdx.x];
  float4 bv4 = ((const float4*)b)[threadIdx.x];
  ushort4 o4;
  o4.x = f2b((v.x - mu) * inv * wv4.x + bv4.x);
  o4.y = f2b((v.y - mu) * inv * wv4.y + bv4.y);
  o4.z = f2b((v.z - mu) * inv * wv4.z + bv4.z);
  o4.w = f2b((v.w - mu) * inv * wv4.w + bv4.w);
  ((ushort4*)(out + (size_t)row * DD))[threadIdx.x] = o4;
}

// ---------------- bf16 MFMA GEMM v2: 2-phase pipelined, BK=64, swizzled LDS --
// C[M,N] = A[M,K] * B[N,K]^T (+bias/gelu/resid) or fp32 partial (split-K).
// 128x128 tile, 256 threads (4 waves 2x2), double-buffered 64KB LDS.
template<int FUSE_GELU, int OUT_BF16, int HAS_RESID, int PARTIAL>
__global__ __launch_bounds__(256) void gemm2(
    const unsigned short* __restrict__ A,   // [M,K] bf16
    const unsigned short* __restrict__ Bw,  // [N,K] bf16
    const float* __restrict__ bias,         // [N]
    const float* __restrict__ resid,        // [M,N] fp32
    void* __restrict__ Cout,
    int M, int N, int K, int KS) {
  __shared__ char lds[65536];  // buf0: A 0..16K, B 16..32K; buf1: 32..48K, 48..64K
  const int tid = threadIdx.x;
  const int w = tid >> 6, l = tid & 63;
  const int l15 = l & 15, lhi = l >> 4;
  const int row0 = blockIdx.y * 128, col0 = blockIdx.x * 128;
  const int kbeg = blockIdx.z * KS;
  const int wm = (w >> 1) * 64, wn = (w & 1) * 64;

  f32x4 acc[4][4] = {};

  // staging geometry: wave w covers rows w*32..w*32+31 (4 issues of 8 rows).
  // LDS row = 128B; source col pre-swizzled so a plain XOR on read is conflict-free.
  const int lrow = l >> 3;                       // 0..7 (== row&7 for all issues)
  const int cb = ((l & 7) * 16) ^ (lrow << 4);   // swizzled source byte col
  const size_t rs8 = (size_t)K * 16;             // 8 rows, in bytes
  const char* aS = (const char*)A + ((size_t)(row0 + w * 32 + lrow) * K + kbeg) * 2 + cb;
  const char* bS = (const char*)Bw + ((size_t)(col0 + w * 32 + lrow) * K + kbeg) * 2 + cb;
  char* aD = lds + w * 4096;
  char* bD = lds + 16384 + w * 4096;

  const int NT = KS >> 6;

  // prologue: stage tile 0 into buf0
#pragma unroll
  for (int i = 0; i < 4; ++i) {
    GLDS16(aS + i * rs8, aD + i * 1024);
    GLDS16(bS + i * rs8, bD + i * 1024);
  }
  aS += 128; bS += 128;
  __syncthreads();

  int cur = 0;
  for (int t = 0; t < NT; ++t) {
    if (t + 1 < NT) {            // issue next-tile loads BEFORE computing
      char* aDn = aD + (cur ^ 1) * 32768;
      char* bDn = bD + (cur ^ 1) * 32768;
#pragma unroll
      for (int i = 0; i < 4; ++i) {
        GLDS16(aS + i * rs8, aDn + i * 1024);
        GLDS16(bS + i * rs8, bDn + i * 1024);
      }
      aS += 128; bS += 128;
    }
    const char* Ab = lds + cur * 32768;
    const char* Bb = Ab + 16384;
    const int swz = (l15 & 7) << 4;
#pragma unroll
    for (int kk = 0; kk < 2; ++kk) {
      short8 af[4], bf[4];
#pragma unroll
      for (int mi = 0; mi < 4; ++mi)
        af[mi] = *(const short8*)(Ab + (wm + mi * 16 + l15) * 128 + ((kk * 64 + lhi * 16) ^ swz));
#pragma unroll
      for (int ni = 0; ni < 4; ++ni)
        bf[ni] = *(const short8*)(Bb + (wn + ni * 16 + l15) * 128 + ((kk * 64 + lhi * 16) ^ swz));
#pragma unroll
      for (int mi = 0; mi < 4; ++mi)
#pragma unroll
        for (int ni = 0; ni < 4; ++ni)
          acc[mi][ni] = MFMA16(af[mi], bf[ni], acc[mi][ni]);
    }
    __syncthreads();             // drains vmcnt(0): staged tile ready
    cur ^= 1;
  }

  if (PARTIAL) {
    float* Cp = (float*)Cout + (size_t)blockIdx.z * M * N;
#pragma unroll
    for (int mi = 0; mi < 4; ++mi)
#pragma unroll
      for (int r = 0; r < 4; ++r) {
        size_t row = (size_t)(row0 + wm + mi * 16 + lhi * 4 + r);
#pragma unroll
        for (int ni = 0; ni < 4; ++ni)
          Cp[row * N + col0 + wn + ni * 16 + l15] = acc[mi][ni][r];
      }
    return;
  }

#pragma unroll
  for (int mi = 0; mi < 4; ++mi) {
#pragma unroll
    for (int r = 0; r < 4; ++r) {
      size_t row = (size_t)(row0 + wm + mi * 16 + lhi * 4 + r);
#pragma unroll
      for (int ni = 0; ni < 4; ++ni) {
        int col = col0 + wn + ni * 16 + l15;
        float v = acc[mi][ni][r] + bias[col];
        if (FUSE_GELU) {
          float u = v;
          v = 0.5f * u * (1.0f + tanhf(0.7978845608028654f * (u + 0.044715f * u * u * u)));
        }
        if (HAS_RESID) v += resid[row * N + col];
        if (OUT_BF16) ((unsigned short*)Cout)[row * N + col] = f2b(v);
        else          ((float*)Cout)[row * N + col] = v;
      }
    }
  }
}

// ---------------- split-K reduce for down-proj: out = resid + bias + p0 + p1 --
__global__ __launch_bounds__(256) void reduce_down(const float* __restrict__ p,
    const float* __restrict__ bias, const float* __restrict__ resid,
    float* __restrict__ out) {
  int i = blockIdx.x * 256 + threadIdx.x;        // over T*D/4
  float4 a = ((const float4*)p)[i];
  float4 b = ((const float4*)(p + (size_t)TT * DD))[i];
  float4 r = ((const float4*)resid)[i];
  float4 bb = ((const float4*)bias)[i & (DD / 4 - 1)];
  float4 o;
  o.x = a.x + b.x + r.x + bb.x;
  o.y = a.y + b.y + r.y + bb.y;
  o.z = a.z + b.z + r.z + bb.z;
  o.w = a.w + b.w + r.w + bb.w;
  ((float4*)out)[i] = o;
}

// ---------------- gather heads: kqv[T,3D] bf16 -> K/Q/V [H,T,DH] bf16 --------
__global__ __launch_bounds__(256) void gather_qkv(const unsigned short* __restrict__ kqv,
    unsigned short* __restrict__ Q, unsigned short* __restrict__ K,
    unsigned short* __restrict__ V) {
  int idx = blockIdx.x * 256 + threadIdx.x;   // over H*T*DH = 2^21
  int d = idx & 63;
  int t = (idx >> 6) & (TT - 1);
  int h = idx >> 17;
  int col = d * NH + h;
  const unsigned short* rowp = kqv + (size_t)t * (3 * DD);
  K[idx] = rowp[col];
  Q[idx] = f2b(b2f(rowp[DD + col]) * 8.0f);   // * sqrt(DH), exact in bf16
  V[idx] = rowp[2 * DD + col];
}

// ---------------- MFMA flash attention (unchanged from round 2) -------------
__global__ __launch_bounds__(256) void attn_mfma(
    const unsigned short* __restrict__ Q,   // [H,T,DH] bf16, pre-scaled
    const unsigned short* __restrict__ K,
    const unsigned short* __restrict__ V,
    unsigned short* __restrict__ hv) {      // [T,D] bf16, head-slow cols
  const int h = blockIdx.y;
  const int qb = gridDim.x - 1 - blockIdx.x;   // heavy blocks first
  const int q0 = qb * 64;
  const int tid = threadIdx.x;
  const int w = tid >> 6, l = tid & 63;
  const int l15 = l & 15, lhi = l >> 4;

  __shared__ unsigned short Ks[64 * 64];       // swizzled [key][dim]
  __shared__ unsigned short Vt[64 * 64];       // swizzled [dim][key]
  __shared__ unsigned short Ps[4][16 * 64];    // per-wave [16 q][64 k] swizzled

  const unsigned short* Kh = K + (size_t)h * TT * DHD;
  const unsigned short* Vh = V + (size_t)h * TT * DHD;

  const unsigned short* Qbase = Q + ((size_t)h * TT + q0 + w * 16 + l15) * DHD;
  short8 qf0 = *(const short8*)(Qbase + lhi * 8);
  short8 qf1 = *(const short8*)(Qbase + 32 + lhi * 8);

  f32x4 oacc[4] = {};
  float m[4], lsum[4];
#pragma unroll
  for (int r = 0; r < 4; ++r) { m[r] = -INFINITY; lsum[r] = 0.0f; }

  const int krow = w * 16 + (l >> 3);
  const int kswz = (krow & 7) << 4;
  const int kcolb = ((l & 7) * 16) ^ kswz;
  char* kL = (char*)Ks + w * 2048;

  for (int kt = 0; kt <= qb; ++kt) {
    const int k0 = kt * 64;
    __syncthreads();

    GLDS16((const char*)(Kh + (size_t)(k0 + krow) * DHD) + kcolb, kL);
    GLDS16((const char*)(Kh + (size_t)(k0 + krow + 8) * DHD) + kcolb, kL + 1024);

    {
      const char* vS = (const char*)(Vh + (size_t)(k0 + l) * DHD) + w * 16;
      short8 v0 = *(const short8*)vS;
      short8 v1 = *(const short8*)(vS + 64);
#pragma unroll
      for (int j = 0; j < 8; ++j) {
        int d = w * 8 + j;
        *(unsigned short*)((char*)Vt + d * 128 + ((2 * l) ^ (j << 4))) =
            (unsigned short)v0[j];
        *(unsigned short*)((char*)Vt + (d + 32) * 128 + ((2 * l) ^ (j << 4))) =
            (unsigned short)v1[j];
      }
    }
    __syncthreads();

    f32x4 sacc[4] = {};
    {
      const char* kr = (const char*)Ks;
      int swz = (l15 & 7) << 4;
#pragma unroll
      for (int nt = 0; nt < 4; ++nt) {
        const char* rowp = kr + (nt * 16 + l15) * 128;
        short8 kb0 = *(const short8*)(rowp + ((lhi * 16) ^ swz));
        short8 kb1 = *(const short8*)(rowp + ((64 + lhi * 16) ^ swz));
        sacc[nt] = MFMA16(qf0, kb0, sacc[nt]);
        sacc[nt] = MFMA16(qf1, kb1, sacc[nt]);
      }
    }

    if (kt == qb) {
      const int qrow = w * 16 + lhi * 4;
#pragma unroll
      for (int nt = 0; nt < 4; ++nt)
#pragma unroll
        for (int r = 0; r < 4; ++r)
          if (nt * 16 + l15 > qrow + r) sacc[nt][r] = -INFINITY;
    }

    float mnew[4], al[4];
#pragma unroll
    for (int r = 0; r < 4; ++r) {
      float t = fmaxf(fmaxf(sacc[0][r], sacc[1][r]), fmaxf(sacc[2][r], sacc[3][r]));
      t = fmaxf(t, __shfl_xor(t, 1));
      t = fmaxf(t, __shfl_xor(t, 2));
      t = fmaxf(t, __shfl_xor(t, 4));
      t = fmaxf(t, __shfl_xor(t, 8));
      mnew[r] = fmaxf(m[r], t);
      al[r] = __expf(m[r] - mnew[r]);
      m[r] = mnew[r];
    }
#pragma unroll
    for (int r = 0; r < 4; ++r) {
      float s = 0.0f;
#pragma unroll
      for (int nt = 0; nt < 4; ++nt) {
        float p = __expf(sacc[nt][r] - mnew[r]);
        sacc[nt][r] = p;
        s += p;
      }
      s += __shfl_xor(s, 1);
      s += __shfl_xor(s, 2);
      s += __shfl_xor(s, 4);
      s += __shfl_xor(s, 8);
      lsum[r] = lsum[r] * al[r] + s;
#pragma unroll
      for (int dt = 0; dt < 4; ++dt) oacc[dt][r] *= al[r];
    }

    {
      char* pw = (char*)Ps[w];
#pragma unroll
      for (int r = 0; r < 4; ++r) {
        int prow = lhi * 4 + r;
        char* pp = pw + prow * 128;
        int swz = (prow & 7) << 4;
#pragma unroll
        for (int nt = 0; nt < 4; ++nt)
          *(unsigned short*)(pp + ((nt * 32 + l15 * 2) ^ swz)) = f2b(sacc[nt][r]);
      }
    }

    {
      const char* pr = (const char*)Ps[w] + l15 * 128;
      int pswz = (l15 & 7) << 4;
      short8 pa0 = *(const short8*)(pr + ((lhi * 16) ^ pswz));
      short8 pa1 = *(const short8*)(pr + ((64 + lhi * 16) ^ pswz));
      int vswz = (l15 & 7) << 4;
#pragma unroll
      for (int dt = 0; dt < 4; ++dt) {
        const char* vr = (const char*)Vt + (dt * 16 + l15) * 128;
        short8 vb0 = *(const short8*)(vr + ((lhi * 16) ^ vswz));
        short8 vb1 = *(const short8*)(vr + ((64 + lhi * 16) ^ vswz));
        oacc[dt] = MFMA16(pa0, vb0, oacc[dt]);
        oacc[dt] = MFMA16(pa1, vb1, oacc[dt]);
      }
    }
  }

#pragma unroll
  for (int r = 0; r < 4; ++r) {
    float inv = 1.0f / lsum[r];
    size_t orow = (size_t)(q0 + w * 16 + lhi * 4 + r) * DD + h * 64;
#pragma unroll
    for (int dt = 0; dt < 4; ++dt)
      hv[orow + dt * 16 + l15] = f2b(oacc[dt][r] * inv);
  }
}

// ---------------- launch ----------------
extern "C" void kernel_launch(void* const* d_in, const int* in_sizes, int n_in,
                              void* d_out, int out_size, void* d_ws, size_t ws_size,
                              hipStream_t stream) {
  const float* x     = (const float*)d_in[0];
  const float* w_kqv = (const float*)d_in[1];
  const float* b_kqv = (const float*)d_in[2];
  const float* w_o   = (const float*)d_in[3];
  const float* b_o   = (const float*)d_in[4];
  const float* ln1_w = (const float*)d_in[5];
  const float* ln1_b = (const float*)d_in[6];
  const float* ln2_w = (const float*)d_in[7];
  const float* ln2_b = (const float*)d_in[8];
  const float* w_up  = (const float*)d_in[9];
  const float* b_up  = (const float*)d_in[10];
  const float* w_dn  = (const float*)d_in[11];
  const float* b_dn  = (const float*)d_in[12];
  float* out = (float*)d_out;

  char* W = (char*)d_ws;
  unsigned short* wkqv_b = (unsigned short*)(W);                 // 6 MB
  unsigned short* wo_b   = (unsigned short*)(W + 6291456);       // 2 MB
  unsigned short* wup_b  = (unsigned short*)(W + 8388608);       // 8 MB
  unsigned short* wdn_b  = (unsigned short*)(W + 16777216);      // 8 MB
  unsigned short* h_b    = (unsigned short*)(W + 25165824);      // 4 MB
  unsigned short* kqz    = (unsigned short*)(W + 29360128);      // 16 MB (kqv, then z1)
  unsigned short* Qg     = (unsigned short*)(W + 46137344);      // 4 MB
  unsigned short* Kg     = (unsigned short*)(W + 50331648);      // 4 MB
  unsigned short* Vg     = (unsigned short*)(W + 54525952);      // 4 MB
  unsigned short* hv_b   = (unsigned short*)(W + 58720256);      // 4 MB
  float*          x2     = (float*)(W + 62914560);               // 8 MB
  float*          part   = (float*)(W + 46137344);               // 16 MB, reuses Qg..hv (dead)

  // weight conversion fp32 -> bf16
  f2b_kernel<<<(3 * DD * DD / 4 + 255) / 256, 256, 0, stream>>>(w_kqv, wkqv_b, 3 * DD * DD / 4);
  f2b_kernel<<<(DD * DD / 4 + 255) / 256, 256, 0, stream>>>(w_o, wo_b, DD * DD / 4);
  f2b_kernel<<<(DFF * DD / 4 + 255) / 256, 256, 0, stream>>>(w_up, wup_b, DFF * DD / 4);
  f2b_kernel<<<(DD * DFF / 4 + 255) / 256, 256, 0, stream>>>(w_dn, wdn_b, DD * DFF / 4);

  // 1. h = LN1(x)
  ln_kernel<<<TT, 256, 0, stream>>>(x, ln1_w, ln1_b, h_b);
  // 2. kqv = h @ w_kqv^T + b_kqv   (bf16 out)
  gemm2<0, 1, 0, 0><<<dim3(3 * DD / 128, TT / 128, 1), 256, 0, stream>>>(
      h_b, wkqv_b, b_kqv, nullptr, kqz, TT, 3 * DD, DD, DD);
  // 3. gather heads (Q pre-scaled by sqrt(DH))
  gather_qkv<<<(NH * TT * DHD) / 256, 256, 0, stream>>>(kqz, Qg, Kg, Vg);
  // 4. attention -> hv bf16
  attn_mfma<<<dim3(TT / 64, NH), 256, 0, stream>>>(Qg, Kg, Vg, hv_b);
  // 5. x2 = x + hv @ w_o^T + b_o   (fp32 out)
  gemm2<0, 0, 1, 0><<<dim3(DD / 128, TT / 128, 1), 256, 0, stream>>>(
      hv_b, wo_b, b_o, x, x2, TT, DD, DD, DD);
  // 6. h2 = LN2(x2)
  ln_kernel<<<TT, 256, 0, stream>>>(x2, ln2_w, ln2_b, h_b);
  // 7. z1 = gelu(h2 @ w_up^T + b_up)  (bf16 out)
  gemm2<1, 1, 0, 0><<<dim3(DFF / 128, TT / 128, 1), 256, 0, stream>>>(
      h_b, wup_b, b_up, nullptr, kqz, TT, DFF, DD, DD);
  // 8a. down-proj split-K=2: fp32 partials
  gemm2<0, 0, 0, 1><<<dim3(DD / 128, TT / 128, 2), 256, 0, stream>>>(
      kqz, wdn_b, nullptr, nullptr, part, TT, DD, DFF, DFF / 2);
  // 8b. out = x2 + b_dn + p0 + p1
  reduce_down<<<TT * DD / 4 / 256, 256, 0, stream>>>(part, b_dn, x2, out);
}

// Round 4
// 179.836 us; speedup vs baseline: 13.4324x; 1.1750x over previous
//
#include <hip/hip_runtime.h>
#include <math.h>

#define TT 2048
#define DD 1024
#define NH 16
#define DHD 64
#define DFF 4096

typedef __attribute__((ext_vector_type(8))) short short8;
typedef __attribute__((ext_vector_type(4))) float f32x4;

#define MFMA16(a, b, c) __builtin_amdgcn_mfma_f32_16x16x32_bf16(a, b, c, 0, 0, 0)
#define GLDS16(gp, lp) __builtin_amdgcn_global_load_lds( \
    (const __attribute__((address_space(1))) void*)(gp), \
    (__attribute__((address_space(3))) void*)(lp), 16, 0, 0)

static __device__ __forceinline__ unsigned short f2b(float f) {
  unsigned u = __builtin_bit_cast(unsigned, f);
  u = u + 0x7fffu + ((u >> 16) & 1u);
  return (unsigned short)(u >> 16);
}
static __device__ __forceinline__ float b2f(unsigned short b) {
  return __builtin_bit_cast(float, (unsigned)b << 16);
}

// ---------------- fp32 -> bf16 convert: all 4 weight mats, one launch -------
// outputs are contiguous in ws: wkqv(3M f4) | wo(1M... sizes in float4 units:
// wkqv 786432, wo 262144, wup 1048576, wdn 1048576 -> total 3145728
__global__ __launch_bounds__(256) void f2b4_kernel(const float* __restrict__ s0,
    const float* __restrict__ s1, const float* __restrict__ s2,
    const float* __restrict__ s3, unsigned short* __restrict__ out) {
  int i = blockIdx.x * 256 + threadIdx.x;
  const float* s; int off;
  if (i < 786432)       { s = s0; off = 0; }
  else if (i < 1048576) { s = s1; off = 786432; }
  else if (i < 2097152) { s = s2; off = 1048576; }
  else                  { s = s3; off = 2097152; }
  float4 v = ((const float4*)s)[i - off];
  ushort4 o;
  o.x = f2b(v.x); o.y = f2b(v.y); o.z = f2b(v.z); o.w = f2b(v.w);
  ((ushort4*)out)[i] = o;
}

// ---------------- LayerNorm (fp32 in, bf16 out) ----------------
__global__ __launch_bounds__(256) void ln_kernel(const float* __restrict__ x,
    const float* __restrict__ w, const float* __restrict__ b,
    unsigned short* __restrict__ out) {
  int row = blockIdx.x;
  const float4* xr = (const float4*)(x + (size_t)row * DD);
  float4 v = xr[threadIdx.x];
  float s  = v.x + v.y + v.z + v.w;
  float ss = v.x * v.x + v.y * v.y + v.z * v.z + v.w * v.w;
  for (int o = 32; o > 0; o >>= 1) {
    s  += __shfl_down(s, o);
    ss += __shfl_down(ss, o);
  }
  __shared__ float red[10];
  int lane = threadIdx.x & 63, wv = threadIdx.x >> 6;
  if (lane == 0) { red[wv] = s; red[4 + wv] = ss; }
  __syncthreads();
  if (threadIdx.x == 0) {
    float S  = red[0] + red[1] + red[2] + red[3];
    float SS = red[4] + red[5] + red[6] + red[7];
    float mu  = S * (1.0f / DD);
    float var = SS * (1.0f / DD) - mu * mu;
    red[8] = mu;
    red[9] = rsqrtf(var + 1e-5f);
  }
  __syncthreads();
  float mu = red[8], inv = red[9];
  float4 wv4 = ((const float4*)w)[threadIdx.x];
  float4 bv4 = ((const float4*)b)[threadIdx.x];
  ushort4 o4;
  o4.x = f2b((v.x - mu) * inv * wv4.x + bv4.x);
  o4.y = f2b((v.y - mu) * inv * wv4.y + bv4.y);
  o4.z = f2b((v.z - mu) * inv * wv4.z + bv4.z);
  o4.w = f2b((v.w - mu) * inv * wv4.w + bv4.w);
  ((ushort4*)(out + (size_t)row * DD))[threadIdx.x] = o4;
}

// ---------------- bf16 MFMA GEMM: 2-phase pipelined, BK=64, swizzled LDS ----
template<int FUSE_GELU, int OUT_BF16, int HAS_RESID, int PARTIAL>
__global__ __launch_bounds__(256) void gemm2(
    const unsigned short* __restrict__ A,   // [M,K] bf16
    const unsigned short* __restrict__ Bw,  // [N,K] bf16
    const float* __restrict__ bias,         // [N]
    const float* __restrict__ resid,        // [M,N] fp32
    void* __restrict__ Cout,
    int M, int N, int K, int KS) {
  __shared__ char lds[65536];
  const int tid = threadIdx.x;
  const int w = tid >> 6, l = tid & 63;
  const int l15 = l & 15, lhi = l >> 4;
  const int row0 = blockIdx.y * 128, col0 = blockIdx.x * 128;
  const int kbeg = blockIdx.z * KS;
  const int wm = (w >> 1) * 64, wn = (w & 1) * 64;

  f32x4 acc[4][4] = {};

  const int lrow = l >> 3;
  const int cb = ((l & 7) * 16) ^ (lrow << 4);
  const size_t rs8 = (size_t)K * 16;
  const char* aS = (const char*)A + ((size_t)(row0 + w * 32 + lrow) * K + kbeg) * 2 + cb;
  const char* bS = (const char*)Bw + ((size_t)(col0 + w * 32 + lrow) * K + kbeg) * 2 + cb;
  char* aD = lds + w * 4096;
  char* bD = lds + 16384 + w * 4096;

  const int NT = KS >> 6;

#pragma unroll
  for (int i = 0; i < 4; ++i) {
    GLDS16(aS + i * rs8, aD + i * 1024);
    GLDS16(bS + i * rs8, bD + i * 1024);
  }
  aS += 128; bS += 128;
  __syncthreads();

  int cur = 0;
  for (int t = 0; t < NT; ++t) {
    if (t + 1 < NT) {
      char* aDn = aD + (cur ^ 1) * 32768;
      char* bDn = bD + (cur ^ 1) * 32768;
#pragma unroll
      for (int i = 0; i < 4; ++i) {
        GLDS16(aS + i * rs8, aDn + i * 1024);
        GLDS16(bS + i * rs8, bDn + i * 1024);
      }
      aS += 128; bS += 128;
    }
    const char* Ab = lds + cur * 32768;
    const char* Bb = Ab + 16384;
    const int swz = (l15 & 7) << 4;
#pragma unroll
    for (int kk = 0; kk < 2; ++kk) {
      short8 af[4], bf[4];
#pragma unroll
      for (int mi = 0; mi < 4; ++mi)
        af[mi] = *(const short8*)(Ab + (wm + mi * 16 + l15) * 128 + ((kk * 64 + lhi * 16) ^ swz));
#pragma unroll
      for (int ni = 0; ni < 4; ++ni)
        bf[ni] = *(const short8*)(Bb + (wn + ni * 16 + l15) * 128 + ((kk * 64 + lhi * 16) ^ swz));
#pragma unroll
      for (int mi = 0; mi < 4; ++mi)
#pragma unroll
        for (int ni = 0; ni < 4; ++ni)
          acc[mi][ni] = MFMA16(af[mi], bf[ni], acc[mi][ni]);
    }
    __syncthreads();
    cur ^= 1;
  }

  if (PARTIAL) {
    float* Cp = (float*)Cout + (size_t)blockIdx.z * M * N;
#pragma unroll
    for (int mi = 0; mi < 4; ++mi)
#pragma unroll
      for (int r = 0; r < 4; ++r) {
        size_t row = (size_t)(row0 + wm + mi * 16 + lhi * 4 + r);
#pragma unroll
        for (int ni = 0; ni < 4; ++ni)
          Cp[row * N + col0 + wn + ni * 16 + l15] = acc[mi][ni][r];
      }
    return;
  }

#pragma unroll
  for (int mi = 0; mi < 4; ++mi) {
#pragma unroll
    for (int r = 0; r < 4; ++r) {
      size_t row = (size_t)(row0 + wm + mi * 16 + lhi * 4 + r);
#pragma unroll
      for (int ni = 0; ni < 4; ++ni) {
        int col = col0 + wn + ni * 16 + l15;
        float v = acc[mi][ni][r] + bias[col];
        if (FUSE_GELU) {
          float u = v;
          v = 0.5f * u * (1.0f + tanhf(0.7978845608028654f * (u + 0.044715f * u * u * u)));
        }
        if (HAS_RESID) v += resid[row * N + col];
        if (OUT_BF16) ((unsigned short*)Cout)[row * N + col] = f2b(v);
        else          ((float*)Cout)[row * N + col] = v;
      }
    }
  }
}

// ---------------- split-K reduce for down-proj ----------------
__global__ __launch_bounds__(256) void reduce_down(const float* __restrict__ p,
    const float* __restrict__ bias, const float* __restrict__ resid,
    float* __restrict__ out) {
  int i = blockIdx.x * 256 + threadIdx.x;
  float4 a = ((const float4*)p)[i];
  float4 b = ((const float4*)(p + (size_t)TT * DD))[i];
  float4 r = ((const float4*)resid)[i];
  float4 bb = ((const float4*)bias)[i & (DD / 4 - 1)];
  float4 o;
  o.x = a.x + b.x + r.x + bb.x;
  o.y = a.y + b.y + r.y + bb.y;
  o.z = a.z + b.z + r.z + bb.z;
  o.w = a.w + b.w + r.w + bb.w;
  ((float4*)out)[i] = o;
}

// ---------------- gather heads: kqv[T,3D] bf16 -> K/Q [H,T,DH] bf16 ---------
__global__ __launch_bounds__(256) void gather_qkv(const unsigned short* __restrict__ kqv,
    unsigned short* __restrict__ Q, unsigned short* __restrict__ K) {
  int idx = blockIdx.x * 256 + threadIdx.x;   // over H*T*DH
  int d = idx & 63;
  int t = (idx >> 6) & (TT - 1);
  int h = idx >> 17;
  int col = d * NH + h;
  const unsigned short* rowp = kqv + (size_t)t * (3 * DD);
  K[idx] = rowp[col];
  Q[idx] = f2b(b2f(rowp[DD + col]) * 8.0f);   // * sqrt(DH), exact in bf16
}

// ---------------- V transpose: kqv v-section -> Vt[H][DH][T] ----------------
__global__ __launch_bounds__(256) void transpose_v(const unsigned short* __restrict__ kqv,
    unsigned short* __restrict__ Vt) {
  const int h = blockIdx.y;
  const int t0 = blockIdx.x * 64;
  __shared__ unsigned short Vs[64][65];
  for (int idx = threadIdx.x; idx < 4096; idx += 256) {
    int t = idx >> 6, d = idx & 63;
    Vs[t][d] = kqv[(size_t)(t0 + t) * (3 * DD) + 2 * DD + d * NH + h];
  }
  __syncthreads();
  for (int idx = threadIdx.x; idx < 4096; idx += 256) {
    int d = idx >> 6, t = idx & 63;
    Vt[(size_t)(h * DHD + d) * TT + t0 + t] = Vs[t][d];
  }
}

// ---------------- MFMA flash attention v2 -----------------------------------
// grid (T/64, H), 4 waves; wave w: q rows w*16..+15. Swapped QK^T, dbuf K/V.
__global__ __launch_bounds__(256) void attn_mfma(
    const unsigned short* __restrict__ Q,   // [H,T,DH] bf16, pre-scaled
    const unsigned short* __restrict__ K,   // [H,T,DH]
    const unsigned short* __restrict__ Vt,  // [H,DH,T]
    unsigned short* __restrict__ hv) {      // [T,D] bf16, head-slow cols
  const int h = blockIdx.y;
  const int qb = gridDim.x - 1 - blockIdx.x;   // heavy blocks first
  const int q0 = qb * 64;
  const int tid = threadIdx.x;
  const int w = tid >> 6, l = tid & 63;
  const int l15 = l & 15, lhi = l >> 4;

  __shared__ char lds[40960];   // 2 x (K 8KB | V 8KB) + Ps 8KB (per-wave 2KB)
  char* Ps = lds + 32768 + w * 2048;

  const char* KhB = (const char*)(K + (size_t)h * TT * DHD);
  const char* VhB = (const char*)(Vt + (size_t)h * DHD * TT);

  const unsigned short* Qbase = Q + ((size_t)h * TT + q0 + w * 16 + l15) * DHD;
  short8 qf0 = *(const short8*)(Qbase + lhi * 8);
  short8 qf1 = *(const short8*)(Qbase + 32 + lhi * 8);

  f32x4 oacc[4] = {};
  float m = -1e30f, lsum = 0.0f;

  // staging geometry (pre-swizzled source, linear LDS dest)
  const int lrow = l >> 3;
  const int colb = ((l & 7) * 16) ^ (lrow << 4);
  const int srow = w * 16 + lrow;              // K row / V d-row
  const int swz = (l15 & 7) << 4;

  auto stage = [&](int k0n, char* buf) {
    const char* ks = KhB + (size_t)(k0n + srow) * 128 + colb;
    GLDS16(ks, buf + w * 2048);
    GLDS16(ks + 8 * 128, buf + w * 2048 + 1024);
    const char* vs = VhB + (size_t)srow * (TT * 2) + (size_t)k0n * 2 + colb;
    GLDS16(vs, buf + 8192 + w * 2048);
    GLDS16(vs + 8 * (TT * 2), buf + 8192 + w * 2048 + 1024);
  };

  stage(0, lds);
  __syncthreads();
  int cur = 0;

  for (int kt = 0; kt <= qb; ++kt) {
    if (kt < qb) stage((kt + 1) * 64, lds + (cur ^ 1) * 16384);

    const char* Kb = lds + cur * 16384;
    const char* Vb = Kb + 8192;

    // ---- S^T = K Q^T : sacc[nt][r] = S[key=nt*16+lhi*4+r][q=l15] ----
    f32x4 sacc[4] = {};
    __builtin_amdgcn_s_setprio(1);
#pragma unroll
    for (int nt = 0; nt < 4; ++nt) {
      const char* rp = Kb + (nt * 16 + l15) * 128;
      short8 kb0 = *(const short8*)(rp + ((lhi * 16) ^ swz));
      short8 kb1 = *(const short8*)(rp + ((64 + lhi * 16) ^ swz));
      sacc[nt] = MFMA16(kb0, qf0, sacc[nt]);
      sacc[nt] = MFMA16(kb1, qf1, sacc[nt]);
    }
    __builtin_amdgcn_s_setprio(0);

    if (kt == qb) {          // causal mask on diagonal tile (k0 == q0)
      const int qloc = w * 16 + l15;
#pragma unroll
      for (int nt = 0; nt < 4; ++nt)
#pragma unroll
        for (int r = 0; r < 4; ++r)
          if (nt * 16 + lhi * 4 + r > qloc) sacc[nt][r] = -1e30f;
    }

    // ---- online softmax (q = l15 per lane; reduce over regs + lhi) ----
    float tmax = -1e30f;
#pragma unroll
    for (int nt = 0; nt < 4; ++nt)
#pragma unroll
      for (int r = 0; r < 4; ++r) tmax = fmaxf(tmax, sacc[nt][r]);
    tmax = fmaxf(tmax, __shfl_xor(tmax, 16));
    tmax = fmaxf(tmax, __shfl_xor(tmax, 32));
    float mnew = fmaxf(m, tmax);
    float al = __expf(m - mnew);
    m = mnew;
    float ssum = 0.0f;
#pragma unroll
    for (int nt = 0; nt < 4; ++nt)
#pragma unroll
      for (int r = 0; r < 4; ++r) {
        float p = __expf(sacc[nt][r] - mnew);
        sacc[nt][r] = p;
        ssum += p;
      }
    ssum += __shfl_xor(ssum, 16);
    ssum += __shfl_xor(ssum, 32);
    lsum = lsum * al + ssum;

    // ---- P -> per-wave LDS rows q=l15 (4 x ds_write_b64, swizzled) ----
    {
      char* pp = Ps + l15 * 128;
#pragma unroll
      for (int nt = 0; nt < 4; ++nt) {
        uint2 pk;
        pk.x = (unsigned)f2b(sacc[nt][0]) | ((unsigned)f2b(sacc[nt][1]) << 16);
        pk.y = (unsigned)f2b(sacc[nt][2]) | ((unsigned)f2b(sacc[nt][3]) << 16);
        *(uint2*)(pp + (((nt * 16 + lhi * 4) * 2) ^ swz)) = pk;
      }
    }

    // ---- rescale O (rows q = lhi*4+r; fetch al of that q) ----
    float alr[4];
#pragma unroll
    for (int r = 0; r < 4; ++r) alr[r] = __shfl(al, (l & 48) | (lhi * 4 + r));
#pragma unroll
    for (int dt = 0; dt < 4; ++dt)
#pragma unroll
      for (int r = 0; r < 4; ++r) oacc[dt][r] *= alr[r];

    // ---- O += P V ----
    const char* pr = Ps + l15 * 128;
    short8 pa0 = *(const short8*)(pr + ((lhi * 16) ^ swz));
    short8 pa1 = *(const short8*)(pr + ((64 + lhi * 16) ^ swz));
    __builtin_amdgcn_s_setprio(1);
#pragma unroll
    for (int dt = 0; dt < 4; ++dt) {
      const char* vr = Vb + (dt * 16 + l15) * 128;
      short8 vb0 = *(const short8*)(vr + ((lhi * 16) ^ swz));
      short8 vb1 = *(const short8*)(vr + ((64 + lhi * 16) ^ swz));
      oacc[dt] = MFMA16(pa0, vb0, oacc[dt]);
      oacc[dt] = MFMA16(pa1, vb1, oacc[dt]);
    }
    __builtin_amdgcn_s_setprio(0);

    __syncthreads();
    cur ^= 1;
  }

  // ---- epilogue ----
  float lr[4];
#pragma unroll
  for (int r = 0; r < 4; ++r)
    lr[r] = 1.0f / __shfl(lsum, (l & 48) | (lhi * 4 + r));
#pragma unroll
  for (int r = 0; r < 4; ++r) {
    size_t orow = (size_t)(q0 + w * 16 + lhi * 4 + r) * DD + h * 64;
#pragma unroll
    for (int dt = 0; dt < 4; ++dt)
      hv[orow + dt * 16 + l15] = f2b(oacc[dt][r] * lr[r]);
  }
}

// ---------------- launch ----------------
extern "C" void kernel_launch(void* const* d_in, const int* in_sizes, int n_in,
                              void* d_out, int out_size, void* d_ws, size_t ws_size,
                              hipStream_t stream) {
  const float* x     = (const float*)d_in[0];
  const float* w_kqv = (const float*)d_in[1];
  const float* b_kqv = (const float*)d_in[2];
  const float* w_o   = (const float*)d_in[3];
  const float* b_o   = (const float*)d_in[4];
  const float* ln1_w = (const float*)d_in[5];
  const float* ln1_b = (const float*)d_in[6];
  const float* ln2_w = (const float*)d_in[7];
  const float* ln2_b = (const float*)d_in[8];
  const float* w_up  = (const float*)d_in[9];
  const float* b_up  = (const float*)d_in[10];
  const float* w_dn  = (const float*)d_in[11];
  const float* b_dn  = (const float*)d_in[12];
  float* out = (float*)d_out;

  char* W = (char*)d_ws;
  unsigned short* wkqv_b = (unsigned short*)(W);                 // 6 MB
  unsigned short* wo_b   = (unsigned short*)(W + 6291456);       // 2 MB
  unsigned short* wup_b  = (unsigned short*)(W + 8388608);       // 8 MB
  unsigned short* wdn_b  = (unsigned short*)(W + 16777216);      // 8 MB
  unsigned short* h_b    = (unsigned short*)(W + 25165824);      // 4 MB
  unsigned short* kqz    = (unsigned short*)(W + 29360128);      // 16 MB (kqv, then z1)
  unsigned short* Qg     = (unsigned short*)(W + 46137344);      // 4 MB
  unsigned short* Kg     = (unsigned short*)(W + 50331648);      // 4 MB
  unsigned short* Vtg    = (unsigned short*)(W + 54525952);      // 4 MB [H][DH][T]
  unsigned short* hv_b   = (unsigned short*)(W + 58720256);      // 4 MB
  float*          x2     = (float*)(W + 62914560);               // 8 MB
  float*          part   = (float*)(W + 46137344);               // 16 MB, reuses Qg..hv (dead)

  // weight conversion fp32 -> bf16 (single launch; outputs contiguous)
  f2b4_kernel<<<3145728 / 256, 256, 0, stream>>>(w_kqv, w_o, w_up, w_dn, wkqv_b);

  // 1. h = LN1(x)
  ln_kernel<<<TT, 256, 0, stream>>>(x, ln1_w, ln1_b, h_b);
  // 2. kqv = h @ w_kqv^T + b_kqv   (bf16 out)
  gemm2<0, 1, 0, 0><<<dim3(3 * DD / 128, TT / 128, 1), 256, 0, stream>>>(
      h_b, wkqv_b, b_kqv, nullptr, kqz, TT, 3 * DD, DD, DD);
  // 3. gather heads (Q pre-scaled) + V transpose
  gather_qkv<<<(NH * TT * DHD) / 256, 256, 0, stream>>>(kqz, Qg, Kg);
  transpose_v<<<dim3(TT / 64, NH), 256, 0, stream>>>(kqz, Vtg);
  // 4. attention -> hv bf16
  attn_mfma<<<dim3(TT / 64, NH), 256, 0, stream>>>(Qg, Kg, Vtg, hv_b);
  // 5. x2 = x + hv @ w_o^T + b_o   (fp32 out)
  gemm2<0, 0, 1, 0><<<dim3(DD / 128, TT / 128, 1), 256, 0, stream>>>(
      hv_b, wo_b, b_o, x, x2, TT, DD, DD, DD);
  // 6. h2 = LN2(x2)
  ln_kernel<<<TT, 256, 0, stream>>>(x2, ln2_w, ln2_b, h_b);
  // 7. z1 = gelu(h2 @ w_up^T + b_up)  (bf16 out)
  gemm2<1, 1, 0, 0><<<dim3(DFF / 128, TT / 128, 1), 256, 0, stream>>>(
      h_b, wup_b, b_up, nullptr, kqz, TT, DFF, DD, DD);
  // 8a. down-proj split-K=2: fp32 partials
  gemm2<0, 0, 0, 1><<<dim3(DD / 128, TT / 128, 2), 256, 0, stream>>>(
      kqz, wdn_b, nullptr, nullptr, part, TT, DD, DFF, DFF / 2);
  // 8b. out = x2 + b_dn + p0 + p1
  reduce_down<<<TT * DD / 4 / 256, 256, 0, stream>>>(part, b_dn, x2, out);
}